// Round 1
// baseline (1459.210 us; speedup 1.0000x reference)
//
#include <hip/hip_runtime.h>
#include <hip/hip_bf16.h>
#include <stdint.h>

// Problem constants
#define NUQ 16000
#define NMQ 8000
#define EQ  64
#define LQ  3
#define BQ  100000

// GEMM tiling: M-tile 64, BK=64, K-split 5
#define SPLIT 5
#define MOVIE_BLOCKS (125 * SPLIT)   // 625
#define USER_BLOCKS  (250 * SPLIT)   // 1250
#define GEMM_BLOCKS  (MOVIE_BLOCKS + USER_BLOCKS)  // 1875

typedef short short8 __attribute__((ext_vector_type(8)));
typedef float f32x4  __attribute__((ext_vector_type(4)));
typedef unsigned short ushort_t;

static __device__ __forceinline__ unsigned int bf16_bits(float f) {
    unsigned int u = __float_as_uint(f);
    return (u + 0x7FFFu + ((u >> 16) & 1u)) >> 16;   // RTNE
}
static __device__ __forceinline__ unsigned int pk_bf16(float a, float b) {
    return (bf16_bits(a) & 0xFFFFu) | (bf16_bits(b) << 16);
}

// ---------------------------------------------------------------------------
// prep: transpose-convert embeddings fp32 [K][64] -> bf16 [64][K]
// blocks 0..249: user (K=NU), 250..374: movie (K=NM)
// ---------------------------------------------------------------------------
__global__ __launch_bounds__(256) void prep_kernel(
    const float* __restrict__ uemb, const float* __restrict__ memb,
    ushort_t* __restrict__ uT, ushort_t* __restrict__ mT)
{
    __shared__ float xs[64 * 65];
    int bid = blockIdx.x, t = threadIdx.x;
    bool mside = bid >= 250;
    int k0 = (mside ? (bid - 250) : bid) * 64;
    int ld = mside ? NMQ : NUQ;
    const float* src = mside ? memb : uemb;
    ushort_t* dst = mside ? mT : uT;

    for (int j = 0; j < 16; j++) {
        int idx = j * 256 + t;
        int r = idx >> 6, e = idx & 63;
        xs[r * 65 + e] = src[(size_t)(k0 + r) * 64 + e];
    }
    __syncthreads();
    for (int j = 0; j < 16; j++) {
        int idx = j * 256 + t;
        int e = idx >> 6, rr = idx & 63;
        dst[(size_t)e * ld + k0 + rr] = (ushort_t)bf16_bits(xs[rr * 65 + e]);
    }
}

// ---------------------------------------------------------------------------
// Big GEMM: tmp = adj @ emb   (A fp32/bf16 [M][K], B^T bf16 [64][K])
// MODE 0: read fp32 adj. MODE 1: read fp32, write bf16 copy. MODE 2: read bf16.
// blocks [0,625): movie side, [625,1875): user side. Output: 5 partial slices.
// ---------------------------------------------------------------------------
template <int MODE>
__global__ __launch_bounds__(256) void gemm_kernel(
    const float* __restrict__ adjU, const float* __restrict__ adjM,
    ushort_t* __restrict__ adjUb, ushort_t* __restrict__ adjMb,
    const ushort_t* __restrict__ mT, const ushort_t* __restrict__ uT,
    float* __restrict__ tmp_u, float* __restrict__ tmp_m)
{
    __shared__ ushort_t Ash[64 * 72];
    __shared__ ushort_t Bsh[64 * 72];

    int bid = blockIdx.x, t = threadIdx.x;
    bool movie = bid < MOVIE_BLOCKS;
    int tt = movie ? bid : bid - MOVIE_BLOCKS;
    int mt = tt / SPLIT, ch = tt - mt * SPLIT;
    int M0 = mt * 64;
    int ldK = movie ? NUQ : NMQ;
    int KC  = movie ? (NUQ / SPLIT) : (NMQ / SPLIT);   // 3200 / 1600
    int K0  = ch * KC;
    const float* A = movie ? adjM : adjU;
    ushort_t* Ab = movie ? adjMb : adjUb;
    const ushort_t* BT = movie ? uT : mT;
    float* outp = movie ? (tmp_m + ((size_t)ch * NMQ + M0) * 64)
                        : (tmp_u + ((size_t)ch * NUQ + M0) * 64);

    int srow = t >> 2;            // 0..63
    int scol = (t & 3) * 16;      // 0,16,32,48 (elements)
    size_t arow = (size_t)(M0 + srow) * ldK;
    size_t brow = (size_t)srow * ldK;

    int lane = t & 63, w = t >> 6;
    int R0 = w * 16, mrow = lane & 15, q = lane >> 4;
    const ushort_t* a_base = &Ash[(R0 + mrow) * 72 + q * 8];
    const ushort_t* b_base = &Bsh[mrow * 72 + q * 8];

    f32x4 acc[4];
#pragma unroll
    for (int nb = 0; nb < 4; nb++) acc[nb] = (f32x4){0.f, 0.f, 0.f, 0.f};

    for (int kk = K0; kk < K0 + KC; kk += 64) {
        // ---- stage A tile (64 rows x 64 k) ----
        if (MODE == 2) {
            const uint4* src = (const uint4*)(Ab + arow + kk + scol);
            uint4 q0 = src[0], q1 = src[1];
            *(uint4*)&Ash[srow * 72 + scol] = q0;
            *(uint4*)&Ash[srow * 72 + scol + 8] = q1;
        } else {
            const float4* fp = (const float4*)(A + arow + kk + scol);
            float4 f0 = fp[0], f1 = fp[1], f2 = fp[2], f3 = fp[3];
            uint4 q0, q1;
            q0.x = pk_bf16(f0.x, f0.y); q0.y = pk_bf16(f0.z, f0.w);
            q0.z = pk_bf16(f1.x, f1.y); q0.w = pk_bf16(f1.z, f1.w);
            q1.x = pk_bf16(f2.x, f2.y); q1.y = pk_bf16(f2.z, f2.w);
            q1.z = pk_bf16(f3.x, f3.y); q1.w = pk_bf16(f3.z, f3.w);
            *(uint4*)&Ash[srow * 72 + scol] = q0;
            *(uint4*)&Ash[srow * 72 + scol + 8] = q1;
            if (MODE == 1) {
                uint4* d = (uint4*)(Ab + arow + kk + scol);
                d[0] = q0; d[1] = q1;
            }
        }
        // ---- stage B^T tile (64 n x 64 k) ----
        {
            const uint4* src = (const uint4*)(BT + brow + kk + scol);
            uint4 q0 = src[0], q1 = src[1];
            *(uint4*)&Bsh[srow * 72 + scol] = q0;
            *(uint4*)&Bsh[srow * 72 + scol + 8] = q1;
        }
        __syncthreads();
#pragma unroll
        for (int ks = 0; ks < 2; ks++) {
            short8 a = *(const short8*)(a_base + ks * 32);
#pragma unroll
            for (int nb = 0; nb < 4; nb++) {
                short8 b = *(const short8*)(b_base + nb * 16 * 72 + ks * 32);
                acc[nb] = __builtin_amdgcn_mfma_f32_16x16x32_bf16(a, b, acc[nb], 0, 0, 0);
            }
        }
        __syncthreads();
    }
    // epilogue: C/D layout col=lane&15, row=quad*4+reg  [m89-verified]
#pragma unroll
    for (int nb = 0; nb < 4; nb++)
#pragma unroll
        for (int r = 0; r < 4; r++)
            outp[(size_t)(R0 + q * 4 + r) * 64 + nb * 16 + mrow] = acc[nb][r];
}

// ---------------------------------------------------------------------------
// transform: x = sum(5 partials) + prev ; y = lrelu(x @ W.T + 2b)
// writes fp32 table + bf16 transposed table (next GEMM's B^T)
// blocks 0..249: user rows, 250..374: movie rows
// ---------------------------------------------------------------------------
__global__ __launch_bounds__(256) void transform_kernel(
    const float* __restrict__ tmp_u, const float* __restrict__ tmp_m,
    const float* __restrict__ prev_u, const float* __restrict__ prev_m,
    const float* __restrict__ Wu, const float* __restrict__ bu,
    const float* __restrict__ Wm, const float* __restrict__ bm,
    float* __restrict__ out_u, float* __restrict__ out_m,
    ushort_t* __restrict__ uT, ushort_t* __restrict__ mT)
{
    __shared__ float xs[64 * 65];
    __shared__ float Ws[64 * 65];
    __shared__ float ys[64 * 65];
    int bid = blockIdx.x, t = threadIdx.x;
    bool mside = bid >= 250;
    int row0 = (mside ? (bid - 250) : bid) * 64;
    int Nrows = mside ? NMQ : NUQ;
    const float* tmp  = mside ? tmp_m : tmp_u;
    const float* prev = mside ? prev_m : prev_u;
    const float* W    = mside ? Wm : Wu;
    const float* bias = mside ? bm : bu;
    float* outp   = mside ? out_m : out_u;
    ushort_t* outT = mside ? mT : uT;

    for (int j = 0; j < 16; j++) {
        int idx = j * 256 + t;
        int r = idx >> 6, e = idx & 63;
        size_t g = (size_t)(row0 + r) * 64 + e;
        float v = prev[g];
#pragma unroll
        for (int s = 0; s < SPLIT; s++) v += tmp[(size_t)s * Nrows * 64 + g];
        xs[r * 65 + e] = v;
        Ws[r * 65 + e] = W[idx];    // W[e'][e], e'=r
    }
    __syncthreads();

    int ep = t & 63, rb = t >> 6;
    float acc[16];
    float b2 = 2.0f * bias[ep];
#pragma unroll
    for (int j = 0; j < 16; j++) acc[j] = b2;
    for (int e = 0; e < 64; e++) {
        float w = Ws[ep * 65 + e];
#pragma unroll
        for (int j = 0; j < 16; j++) acc[j] += xs[(j * 4 + rb) * 65 + e] * w;
    }
#pragma unroll
    for (int j = 0; j < 16; j++) {
        float v = acc[j];
        v = v > 0.f ? v : 0.01f * v;        // leaky_relu 0.01
        ys[(j * 4 + rb) * 65 + ep] = v;
    }
    __syncthreads();

    for (int j = 0; j < 16; j++) {
        int idx = j * 256 + t;
        int r = idx >> 6, e = idx & 63;
        outp[(size_t)(row0 + r) * 64 + e] = ys[r * 65 + e];
        // transposed bf16 write: e2 = idx>>6 is the emb dim, rr = idx&63 the row
        int e2 = r, rr = e;
        outT[(size_t)e2 * Nrows + row0 + rr] = (ushort_t)bf16_bits(ys[rr * 65 + e2]);
    }
}

// ---------------------------------------------------------------------------
// gather: out[b] = sum_l sum_e u_l[uid[b]][e]*m_l[mid[b]][e]*Wo[l*64+e] + bo
// one wave per sample
// ---------------------------------------------------------------------------
__global__ __launch_bounds__(256) void gather_kernel(
    const float* __restrict__ u0, const float* __restrict__ u1,
    const float* __restrict__ u2, const float* __restrict__ u3,
    const float* __restrict__ m0, const float* __restrict__ m1,
    const float* __restrict__ m2, const float* __restrict__ m3,
    const float* __restrict__ Wo, const float* __restrict__ bo,
    const int* __restrict__ uid, const int* __restrict__ mid,
    float* __restrict__ out)
{
    int t = threadIdx.x;
    int lane = t & 63, wv = t >> 6;
    int b = blockIdx.x * 4 + wv;            // grid = 25000 -> exact B
    size_t ui = (size_t)uid[b] * 64 + lane;
    size_t mi = (size_t)mid[b] * 64 + lane;
    float acc = u0[ui] * m0[mi] * Wo[lane]
              + u1[ui] * m1[mi] * Wo[64 + lane]
              + u2[ui] * m2[mi] * Wo[128 + lane]
              + u3[ui] * m3[mi] * Wo[192 + lane];
#pragma unroll
    for (int off = 32; off >= 1; off >>= 1) acc += __shfl_xor(acc, off, 64);
    if (lane == 0) out[b] = acc + bo[0];
}

// ---------------------------------------------------------------------------
extern "C" void kernel_launch(void* const* d_in, const int* in_sizes, int n_in,
                              void* d_out, int out_size, void* d_ws, size_t ws_size,
                              hipStream_t stream)
{
    const float* adjU = (const float*)d_in[0];
    const float* adjM = (const float*)d_in[1];
    const float* uemb = (const float*)d_in[2];
    const float* memb = (const float*)d_in[3];
    const float* Wu   = (const float*)d_in[4];
    const float* bu   = (const float*)d_in[5];
    const float* Wm   = (const float*)d_in[6];
    const float* bm   = (const float*)d_in[7];
    const float* Wo   = (const float*)d_in[8];
    const float* bo   = (const float*)d_in[9];
    const int* uid    = (const int*)d_in[10];
    const int* mid    = (const int*)d_in[11];
    float* out = (float*)d_out;

    char* ws = (char*)d_ws;
    size_t off = 0;
    auto alloc = [&](size_t bytes) -> void* {
        void* p = ws + off;
        off += (bytes + 255) & ~(size_t)255;
        return p;
    };
    float* u_ws = (float*)alloc((size_t)3 * NUQ * 64 * 4);   // u1,u2,u3
    float* m_ws = (float*)alloc((size_t)3 * NMQ * 64 * 4);   // m1,m2,m3
    ushort_t* uT = (ushort_t*)alloc((size_t)64 * NUQ * 2);   // current layer u^T bf16
    ushort_t* mT = (ushort_t*)alloc((size_t)64 * NMQ * 2);
    float* tmp_u = (float*)alloc((size_t)SPLIT * NUQ * 64 * 4);
    float* tmp_m = (float*)alloc((size_t)SPLIT * NMQ * 64 * 4);
    ushort_t* adjUb = (ushort_t*)alloc((size_t)NUQ * NMQ * 2);
    ushort_t* adjMb = (ushort_t*)alloc((size_t)NMQ * NUQ * 2);
    bool compress = (ws_size >= off);
    if (!compress) { adjUb = nullptr; adjMb = nullptr; }

    prep_kernel<<<375, 256, 0, stream>>>(uemb, memb, uT, mT);

    for (int l = 0; l < LQ; l++) {
        if (compress) {
            if (l == 0)
                gemm_kernel<1><<<GEMM_BLOCKS, 256, 0, stream>>>(adjU, adjM, adjUb, adjMb, mT, uT, tmp_u, tmp_m);
            else
                gemm_kernel<2><<<GEMM_BLOCKS, 256, 0, stream>>>(adjU, adjM, adjUb, adjMb, mT, uT, tmp_u, tmp_m);
        } else {
            gemm_kernel<0><<<GEMM_BLOCKS, 256, 0, stream>>>(adjU, adjM, adjUb, adjMb, mT, uT, tmp_u, tmp_m);
        }
        const float* pu = (l == 0) ? uemb : (u_ws + (size_t)(l - 1) * NUQ * 64);
        const float* pm = (l == 0) ? memb : (m_ws + (size_t)(l - 1) * NMQ * 64);
        transform_kernel<<<375, 256, 0, stream>>>(
            tmp_u, tmp_m, pu, pm,
            Wu + (size_t)l * 64 * 64, bu + (size_t)l * 64,
            Wm + (size_t)l * 64 * 64, bm + (size_t)l * 64,
            u_ws + (size_t)l * NUQ * 64, m_ws + (size_t)l * NMQ * 64,
            uT, mT);
    }

    gather_kernel<<<BQ / 4, 256, 0, stream>>>(
        uemb, u_ws, u_ws + (size_t)NUQ * 64, u_ws + (size_t)2 * NUQ * 64,
        memb, m_ws, m_ws + (size_t)NMQ * 64, m_ws + (size_t)2 * NMQ * 64,
        Wo, bo, uid, mid, out);
}